// Round 3
// baseline (970.503 us; speedup 1.0000x reference)
//
#include <hip/hip_runtime.h>
#include <cmath>

// ConvLSTM2D forward, bf16 MFMA implicit GEMM.
// B=8, T=16, H=W=96, Cin=8, F=64 (4F=256 gates), 3x3 SAME, 16 sequential steps.
// Per step: GEMM M=73728, N=256, K=648. K-steps of 32: 18 h + 3 x (packed taps).
// hpatch row stride padded to 72 ushorts (36 dwords == 4 mod 32) so quad-lane
// A-frag reads spread over all 8 quad-banks (2-way max == free). Stride 64 was
// 0 mod 32 -> 16-way conflict -> 4.2M SQ_LDS_BANK_CONFLICT, ~70% of runtime.

#define HTOT 96
#define WTOT 96
#define CINX 8
#define FF   64
#define G4   256
#define BB   8
#define TT   16
#define HP   72   // padded ushorts per halo position (64 data + 8 pad)

typedef __attribute__((ext_vector_type(8))) short short8;   // 8 bf16 = 4 VGPRs
typedef __attribute__((ext_vector_type(4))) float floatx4;

union U16 { uint4 u; short8 s; };

__device__ __forceinline__ float hsig(float z) {
    return fminf(fmaxf(0.2f * z + 0.5f, 0.f), 1.f);
}

__device__ __forceinline__ float ftanh(float x) {            // |err| ~1e-7, no branches
    float e = __expf(-2.f * fabsf(x));
    float t = (1.f - e) / (1.f + e);
    return copysignf(t, x);
}

__device__ __forceinline__ ushort f2bf(float f) {            // RNE fp32->bf16
    unsigned u = __float_as_uint(f);
    u = (u + 0x7fff + ((u >> 16) & 1)) >> 16;
    return (ushort)u;
}

// ---- prep: x fp32 -> bf16 (all T at once) ----
__global__ __launch_bounds__(256) void conv_x_bf16(const float* __restrict__ x,
                                                   ushort* __restrict__ xbf, int n4) {
    int i = blockIdx.x * 256 + threadIdx.x;
    if (i >= n4) return;
    float4 v = ((const float4*)x)[i];
    ushort4 o;
    o.x = f2bf(v.x); o.y = f2bf(v.y); o.z = f2bf(v.z); o.w = f2bf(v.w);
    ((ushort4*)xbf)[i] = o;
}

// ---- prep: weights fp32 HWIO -> bf16 in B-fragment order ----
__global__ __launch_bounds__(256) void prep_w(const float* __restrict__ Wx,
                                              const float* __restrict__ Wh,
                                              ushort* __restrict__ Bp) {
    int idx = blockIdx.x * 256 + threadIdx.x;
    if (idx >= 21 * 16 * 64) return;
    int lane = idx & 63, nt = (idx >> 6) & 15, s = idx >> 10;
    int q = lane >> 4, col = lane & 15;
    int n = nt * 16 + col;
    ushort o[8];
    if (s < 18) {
        int tap = s >> 1;
        int cbase = (s & 1) * 32 + q * 8;
        #pragma unroll
        for (int j = 0; j < 8; ++j)
            o[j] = f2bf(Wh[((size_t)tap * FF + cbase + j) * G4 + n]);
    } else {
        int tap = (s - 18) * 4 + q;
        #pragma unroll
        for (int j = 0; j < 8; ++j)
            o[j] = (tap < 9) ? f2bf(Wx[((size_t)tap * CINX + j) * G4 + n]) : (ushort)0;
    }
    U16 u;
    #pragma unroll
    for (int j = 0; j < 8; ++j) ((ushort*)&u)[j] = o[j];
    ((uint4*)Bp)[idx] = u.u;
}

// ---- main step kernel: one 8x8 spatial tile x full N=256 per block ----
__global__ __launch_bounds__(256) void convlstm_mfma(
    const ushort* __restrict__ xbf, int t,
    const ushort* __restrict__ hin,
    ushort* __restrict__ hout,
    float* __restrict__ cst,
    const ushort* __restrict__ Bp,
    const float* __restrict__ bias,
    float* __restrict__ out, int last)
{
    __shared__ ushort hpatch[100 * HP];   // 10x10 halo, 64 h-ch + 8 pad per pos
    __shared__ ushort xpatch[100 * 8];    // 10x10 halo, 8 x-ch

    const int tid = threadIdx.x;
    const int x0 = blockIdx.x * 8, y0 = blockIdx.y * 8, bb = blockIdx.z;

    // stage h halo patch (bf16), zero outside borders
    for (int i = tid; i < 800; i += 256) {
        int pos = i >> 3, part = i & 7;
        int py = pos / 10, px = pos - py * 10;
        int gy = y0 - 1 + py, gx = x0 - 1 + px;
        uint4 v = make_uint4(0, 0, 0, 0);
        if (gy >= 0 && gy < HTOT && gx >= 0 && gx < WTOT)
            v = *(const uint4*)(hin + (((size_t)(bb * HTOT + gy)) * WTOT + gx) * FF + part * 8);
        *(uint4*)(hpatch + pos * HP + part * 8) = v;
    }
    // stage x halo patch
    for (int i = tid; i < 100; i += 256) {
        int py = i / 10, px = i - py * 10;
        int gy = y0 - 1 + py, gx = x0 - 1 + px;
        uint4 v = make_uint4(0, 0, 0, 0);
        if (gy >= 0 && gy < HTOT && gx >= 0 && gx < WTOT)
            v = *(const uint4*)(xbf + ((((size_t)bb * TT + t) * HTOT + gy) * WTOT + gx) * CINX);
        *(uint4*)(xpatch + i * 8) = v;
    }

    const int w = tid >> 6, lane = tid & 63, q = lane >> 4, col = lane & 15;

    int pos0[4];
    #pragma unroll
    for (int mt = 0; mt < 4; ++mt)
        pos0[mt] = (2 * mt + (col >> 3)) * 10 + (col & 7);

    // prefetch c-state (read in epilogue) before the K-loop hides its latency
    float cold[16];
    #pragma unroll
    for (int mt = 0; mt < 4; ++mt) {
        #pragma unroll
        for (int r = 0; r < 4; ++r) {
            int p = mt * 16 + q * 4 + r;
            int gy = y0 + (p >> 3), gx = x0 + (p & 7);
            cold[mt * 4 + r] = cst[(((size_t)(bb * HTOT + gy)) * WTOT + gx) * FF + w * 16 + col];
        }
    }

    floatx4 acc[4][4];
    #pragma unroll
    for (int g = 0; g < 4; ++g) {
        float bv = bias[g * 64 + w * 16 + col];
        #pragma unroll
        for (int mt = 0; mt < 4; ++mt)
            acc[mt][g] = (floatx4){bv, bv, bv, bv};
    }

    const uint4* Bp4 = (const uint4*)Bp;

    __syncthreads();

    // ---- h-conv: 18 K-steps of 32, distance-1 prefetch of A and B frags ----
    U16 b4[4], a4[4], b4n[4], a4n[4];
    #pragma unroll
    for (int g = 0; g < 4; ++g)
        b4[g].u = Bp4[(g * 4 + w) * 64 + lane];
    #pragma unroll
    for (int mt = 0; mt < 4; ++mt)
        a4[mt].u = *(const uint4*)(hpatch + pos0[mt] * HP + q * 8);   // tap 0, khalf 0

    #pragma unroll 2
    for (int s = 0; s < 18; ++s) {
        if (s < 17) {
            int s1 = s + 1, tap = s1 >> 1, kh = s1 & 1;
            int dy = tap / 3, dx = tap - 3 * dy;
            #pragma unroll
            for (int g = 0; g < 4; ++g)
                b4n[g].u = Bp4[(s1 * 16 + g * 4 + w) * 64 + lane];
            #pragma unroll
            for (int mt = 0; mt < 4; ++mt)
                a4n[mt].u = *(const uint4*)(hpatch + (pos0[mt] + dy * 10 + dx) * HP + kh * 32 + q * 8);
        }
        #pragma unroll
        for (int mt = 0; mt < 4; ++mt)
            #pragma unroll
            for (int g = 0; g < 4; ++g)
                acc[mt][g] = __builtin_amdgcn_mfma_f32_16x16x32_bf16(a4[mt].s, b4[g].s, acc[mt][g], 0, 0, 0);
        if (s < 17) {
            #pragma unroll
            for (int g = 0; g < 4; ++g) b4[g] = b4n[g];
            #pragma unroll
            for (int mt = 0; mt < 4; ++mt) a4[mt] = a4n[mt];
        }
    }

    // ---- x-conv: 3 K-steps of 32 (4 taps of 8 ch each; quad q selects tap) ----
    #pragma unroll
    for (int s = 0; s < 3; ++s) {
        int tap = s * 4 + q; if (tap > 8) tap = 8;    // tap 9..11: B is zero, clamp addr
        int dy = tap / 3, dx = tap - dy * 3;
        U16 xb[4], xa[4];
        #pragma unroll
        for (int g = 0; g < 4; ++g)
            xb[g].u = Bp4[((18 + s) * 16 + g * 4 + w) * 64 + lane];
        #pragma unroll
        for (int mt = 0; mt < 4; ++mt)
            xa[mt].u = *(const uint4*)(xpatch + (pos0[mt] + dy * 10 + dx) * 8);
        #pragma unroll
        for (int mt = 0; mt < 4; ++mt)
            #pragma unroll
            for (int g = 0; g < 4; ++g)
                acc[mt][g] = __builtin_amdgcn_mfma_f32_16x16x32_bf16(xa[mt].s, xb[g].s, acc[mt][g], 0, 0, 0);
    }

    // ---- epilogue: gates fused in-register (i,f,g,o same lane, different acc) ----
    #pragma unroll
    for (int mt = 0; mt < 4; ++mt) {
        #pragma unroll
        for (int r = 0; r < 4; ++r) {
            int p = mt * 16 + q * 4 + r;              // 0..63; my=p>>3, mx=p&7
            int gy = y0 + (p >> 3), gx = x0 + (p & 7);
            size_t idx = (((size_t)(bb * HTOT + gy)) * WTOT + gx) * FF + w * 16 + col;
            float zi = acc[mt][0][r], zf = acc[mt][1][r];
            float zg = acc[mt][2][r], zo = acc[mt][3][r];
            float cn = hsig(zf) * cold[mt * 4 + r] + hsig(zi) * ftanh(zg);
            cst[idx] = cn;
            float hn = hsig(zo) * ftanh(cn);
            hout[idx] = f2bf(hn);
            if (last) out[idx] = hn;
        }
    }
}

extern "C" void kernel_launch(void* const* d_in, const int* in_sizes, int n_in,
                              void* d_out, int out_size, void* d_ws, size_t ws_size,
                              hipStream_t stream) {
    const float* x  = (const float*)d_in[0];
    const float* Wx = (const float*)d_in[1];
    const float* Wh = (const float*)d_in[2];
    const float* b  = (const float*)d_in[3];

    const size_t NX = (size_t)BB * TT * HTOT * WTOT * CINX;  // 9,437,184
    const size_t NH = (size_t)BB * HTOT * WTOT * FF;         // 4,718,592

    char* ws = (char*)d_ws;
    ushort* xbf  = (ushort*)ws;                 ws += NX * 2;            // 18.9 MB
    ushort* hbf0 = (ushort*)ws;                 ws += NH * 2;            //  9.4 MB
    ushort* hbf1 = (ushort*)ws;                 ws += NH * 2;            //  9.4 MB
    float*  cst  = (float*)ws;                  ws += NH * 4;            // 18.9 MB
    ushort* Bp   = (ushort*)ws;                                          // 344 KB

    hipMemsetAsync(hbf0, 0, NH * 2, stream);
    hipMemsetAsync(cst,  0, NH * 4, stream);

    conv_x_bf16<<<(int)((NX / 4 + 255) / 256), 256, 0, stream>>>(x, xbf, (int)(NX / 4));
    prep_w<<<(21 * 16 * 64 + 255) / 256, 256, 0, stream>>>(Wx, Wh, Bp);

    dim3 grid(WTOT / 8, HTOT / 8, BB);
    for (int t = 0; t < TT; ++t) {
        const ushort* hin = (t & 1) ? hbf1 : hbf0;
        ushort* hout      = (t & 1) ? hbf0 : hbf1;
        convlstm_mfma<<<grid, 256, 0, stream>>>(xbf, t, hin, hout, cst, Bp, b,
                                                (float*)d_out, t == TT - 1);
    }
}

// Round 4
// 850.647 us; speedup vs baseline: 1.1409x; 1.1409x over previous
//
#include <hip/hip_runtime.h>
#include <cmath>

// ConvLSTM2D forward, bf16 MFMA implicit GEMM.
// B=8, T=16, H=W=96, Cin=8, F=64 (4F=256 gates), 3x3 SAME, 16 sequential steps.
// Per step: GEMM M=73728, N=256, K=648. K-steps of 32: 18 h + 3 x (packed taps).
// R4: fit the whole wave state in 128 unified regs (acc 64 in AGPR + B-frag
// cur/next 32 + A-frag 16 + addr) -> __launch_bounds__(256,4) -> 4 waves/SIMD.
// Dropped: cold[] cst prefetch (epilogue loads directly), A-frag double-buffer.

#define HTOT 96
#define WTOT 96
#define CINX 8
#define FF   64
#define G4   256
#define BB   8
#define TT   16
#define HP   72   // padded ushorts per halo position (64 data + 8 pad)

typedef __attribute__((ext_vector_type(8))) short short8;   // 8 bf16 = 4 VGPRs
typedef __attribute__((ext_vector_type(4))) float floatx4;

union U16 { uint4 u; short8 s; };

__device__ __forceinline__ float hsig(float z) {
    return fminf(fmaxf(0.2f * z + 0.5f, 0.f), 1.f);
}

__device__ __forceinline__ float ftanh(float x) {            // |err| ~1e-7, no branches
    float e = __expf(-2.f * fabsf(x));
    float t = (1.f - e) / (1.f + e);
    return copysignf(t, x);
}

__device__ __forceinline__ ushort f2bf(float f) {            // RNE fp32->bf16
    unsigned u = __float_as_uint(f);
    u = (u + 0x7fff + ((u >> 16) & 1)) >> 16;
    return (ushort)u;
}

// ---- prep: x fp32 -> bf16 (all T at once) ----
__global__ __launch_bounds__(256) void conv_x_bf16(const float* __restrict__ x,
                                                   ushort* __restrict__ xbf, int n4) {
    int i = blockIdx.x * 256 + threadIdx.x;
    if (i >= n4) return;
    float4 v = ((const float4*)x)[i];
    ushort4 o;
    o.x = f2bf(v.x); o.y = f2bf(v.y); o.z = f2bf(v.z); o.w = f2bf(v.w);
    ((ushort4*)xbf)[i] = o;
}

// ---- prep: weights fp32 HWIO -> bf16 in B-fragment order ----
__global__ __launch_bounds__(256) void prep_w(const float* __restrict__ Wx,
                                              const float* __restrict__ Wh,
                                              ushort* __restrict__ Bp) {
    int idx = blockIdx.x * 256 + threadIdx.x;
    if (idx >= 21 * 16 * 64) return;
    int lane = idx & 63, nt = (idx >> 6) & 15, s = idx >> 10;
    int q = lane >> 4, col = lane & 15;
    int n = nt * 16 + col;
    ushort o[8];
    if (s < 18) {
        int tap = s >> 1;
        int cbase = (s & 1) * 32 + q * 8;
        #pragma unroll
        for (int j = 0; j < 8; ++j)
            o[j] = f2bf(Wh[((size_t)tap * FF + cbase + j) * G4 + n]);
    } else {
        int tap = (s - 18) * 4 + q;
        #pragma unroll
        for (int j = 0; j < 8; ++j)
            o[j] = (tap < 9) ? f2bf(Wx[((size_t)tap * CINX + j) * G4 + n]) : (ushort)0;
    }
    U16 u;
    #pragma unroll
    for (int j = 0; j < 8; ++j) ((ushort*)&u)[j] = o[j];
    ((uint4*)Bp)[idx] = u.u;
}

// ---- main step kernel: one 8x8 spatial tile x full N=256 per block ----
__global__ __launch_bounds__(256, 4) void convlstm_mfma(
    const ushort* __restrict__ xbf, int t,
    const ushort* __restrict__ hin,
    ushort* __restrict__ hout,
    float* __restrict__ cst,
    const ushort* __restrict__ Bp,
    const float* __restrict__ bias,
    float* __restrict__ out, int last)
{
    __shared__ ushort hpatch[100 * HP];   // 10x10 halo, 64 h-ch + 8 pad per pos
    __shared__ ushort xpatch[100 * 8];    // 10x10 halo, 8 x-ch

    const int tid = threadIdx.x;
    const int x0 = blockIdx.x * 8, y0 = blockIdx.y * 8, bb = blockIdx.z;

    // stage h halo patch (bf16), zero outside borders
    for (int i = tid; i < 800; i += 256) {
        int pos = i >> 3, part = i & 7;
        int py = pos / 10, px = pos - py * 10;
        int gy = y0 - 1 + py, gx = x0 - 1 + px;
        uint4 v = make_uint4(0, 0, 0, 0);
        if (gy >= 0 && gy < HTOT && gx >= 0 && gx < WTOT)
            v = *(const uint4*)(hin + (((size_t)(bb * HTOT + gy)) * WTOT + gx) * FF + part * 8);
        *(uint4*)(hpatch + pos * HP + part * 8) = v;
    }
    // stage x halo patch
    for (int i = tid; i < 100; i += 256) {
        int py = i / 10, px = i - py * 10;
        int gy = y0 - 1 + py, gx = x0 - 1 + px;
        uint4 v = make_uint4(0, 0, 0, 0);
        if (gy >= 0 && gy < HTOT && gx >= 0 && gx < WTOT)
            v = *(const uint4*)(xbf + ((((size_t)bb * TT + t) * HTOT + gy) * WTOT + gx) * CINX);
        *(uint4*)(xpatch + i * 8) = v;
    }

    const int w = tid >> 6, lane = tid & 63, q = lane >> 4, col = lane & 15;

    int pos0[4];
    #pragma unroll
    for (int mt = 0; mt < 4; ++mt)
        pos0[mt] = (2 * mt + (col >> 3)) * 10 + (col & 7);

    floatx4 acc[4][4];
    #pragma unroll
    for (int g = 0; g < 4; ++g) {
        float bv = bias[g * 64 + w * 16 + col];
        #pragma unroll
        for (int mt = 0; mt < 4; ++mt)
            acc[mt][g] = (floatx4){bv, bv, bv, bv};
    }

    const uint4* Bp4 = (const uint4*)Bp;

    __syncthreads();

    // ---- h-conv: 18 K-steps of 32; B (L2) prefetched dist-1, A read in-loop ----
    U16 b4[4], b4n[4];
    #pragma unroll
    for (int g = 0; g < 4; ++g)
        b4[g].u = Bp4[(g * 4 + w) * 64 + lane];

    #pragma unroll 2
    for (int s = 0; s < 18; ++s) {
        if (s < 17) {
            #pragma unroll
            for (int g = 0; g < 4; ++g)
                b4n[g].u = Bp4[((s + 1) * 16 + g * 4 + w) * 64 + lane];
        }
        int tap = s >> 1, kh = s & 1;
        int dy = tap / 3, dx = tap - 3 * dy;
        U16 a4[4];
        #pragma unroll
        for (int mt = 0; mt < 4; ++mt)
            a4[mt].u = *(const uint4*)(hpatch + (pos0[mt] + dy * 10 + dx) * HP + kh * 32 + q * 8);
        #pragma unroll
        for (int mt = 0; mt < 4; ++mt)
            #pragma unroll
            for (int g = 0; g < 4; ++g)
                acc[mt][g] = __builtin_amdgcn_mfma_f32_16x16x32_bf16(a4[mt].s, b4[g].s, acc[mt][g], 0, 0, 0);
        if (s < 17) {
            #pragma unroll
            for (int g = 0; g < 4; ++g) b4[g] = b4n[g];
        }
    }

    // ---- x-conv: 3 K-steps of 32 (4 taps of 8 ch each; quad q selects tap) ----
    #pragma unroll
    for (int s = 0; s < 3; ++s) {
        int tap = s * 4 + q; if (tap > 8) tap = 8;    // tap 9..11: B is zero, clamp addr
        int dy = tap / 3, dx = tap - dy * 3;
        U16 xb[4], xa[4];
        #pragma unroll
        for (int g = 0; g < 4; ++g)
            xb[g].u = Bp4[((18 + s) * 16 + g * 4 + w) * 64 + lane];
        #pragma unroll
        for (int mt = 0; mt < 4; ++mt)
            xa[mt].u = *(const uint4*)(xpatch + (pos0[mt] + dy * 10 + dx) * 8);
        #pragma unroll
        for (int mt = 0; mt < 4; ++mt)
            #pragma unroll
            for (int g = 0; g < 4; ++g)
                acc[mt][g] = __builtin_amdgcn_mfma_f32_16x16x32_bf16(xa[mt].s, xb[g].s, acc[mt][g], 0, 0, 0);
    }

    // ---- epilogue: gates fused in-register (i,f,g,o same lane, different acc) ----
    #pragma unroll
    for (int mt = 0; mt < 4; ++mt) {
        #pragma unroll
        for (int r = 0; r < 4; ++r) {
            int p = mt * 16 + q * 4 + r;              // 0..63; my=p>>3, mx=p&7
            int gy = y0 + (p >> 3), gx = x0 + (p & 7);
            size_t idx = (((size_t)(bb * HTOT + gy)) * WTOT + gx) * FF + w * 16 + col;
            float zi = acc[mt][0][r], zf = acc[mt][1][r];
            float zg = acc[mt][2][r], zo = acc[mt][3][r];
            float cn = hsig(zf) * cst[idx] + hsig(zi) * ftanh(zg);
            cst[idx] = cn;
            float hn = hsig(zo) * ftanh(cn);
            hout[idx] = f2bf(hn);
            if (last) out[idx] = hn;
        }
    }
}

extern "C" void kernel_launch(void* const* d_in, const int* in_sizes, int n_in,
                              void* d_out, int out_size, void* d_ws, size_t ws_size,
                              hipStream_t stream) {
    const float* x  = (const float*)d_in[0];
    const float* Wx = (const float*)d_in[1];
    const float* Wh = (const float*)d_in[2];
    const float* b  = (const float*)d_in[3];

    const size_t NX = (size_t)BB * TT * HTOT * WTOT * CINX;  // 9,437,184
    const size_t NH = (size_t)BB * HTOT * WTOT * FF;         // 4,718,592

    char* ws = (char*)d_ws;
    ushort* xbf  = (ushort*)ws;                 ws += NX * 2;            // 18.9 MB
    ushort* hbf0 = (ushort*)ws;                 ws += NH * 2;            //  9.4 MB
    ushort* hbf1 = (ushort*)ws;                 ws += NH * 2;            //  9.4 MB
    float*  cst  = (float*)ws;                  ws += NH * 4;            // 18.9 MB
    ushort* Bp   = (ushort*)ws;                                          // 344 KB

    hipMemsetAsync(hbf0, 0, NH * 2, stream);
    hipMemsetAsync(cst,  0, NH * 4, stream);

    conv_x_bf16<<<(int)((NX / 4 + 255) / 256), 256, 0, stream>>>(x, xbf, (int)(NX / 4));
    prep_w<<<(21 * 16 * 64 + 255) / 256, 256, 0, stream>>>(Wx, Wh, Bp);

    dim3 grid(WTOT / 8, HTOT / 8, BB);
    for (int t = 0; t < TT; ++t) {
        const ushort* hin = (t & 1) ? hbf1 : hbf0;
        ushort* hout      = (t & 1) ? hbf0 : hbf1;
        convlstm_mfma<<<grid, 256, 0, stream>>>(xbf, t, hin, hout, cst, Bp, b,
                                                (float*)d_out, t == TT - 1);
    }
}

// Round 5
// 735.224 us; speedup vs baseline: 1.3200x; 1.1570x over previous
//
#include <hip/hip_runtime.h>
#include <cmath>

// ConvLSTM2D forward, bf16 MFMA implicit GEMM, R5: LDS-shared B + slice-major state.
// B=8, T=16, H=W=96, Cin=8, F=64 (4F=256 gates), 3x3 SAME, 16 sequential steps.
// Per step GEMM: M=73728, N=256, K=672 (21 K-steps of 32: 18 h-taps + 3 packed x).
// Block tile: M=128 (16x8 spatial) x N=64 (fch 16-slice x 4 gates); wave = M=32.
// Weights: per-slice contiguous slab stream (21 x 4KB), double-buffered via LDS,
// loaded once per block (B L2 traffic 594 -> 194 MB/step vs R4's per-wave loads).
// h/c state slice-major [slice][pos][16ch] -> contiguous 512B epilogue runs.

#define HTOT 96
#define WTOT 96
#define CINX 8
#define FF   64
#define G4   256
#define BB   8
#define TT   16
#define HP   72                    // padded ushorts per halo position
#define NPOS (BB*HTOT*WTOT)        // 73728 global positions

typedef __attribute__((ext_vector_type(8))) short short8;   // 8 bf16 = 4 VGPRs
typedef __attribute__((ext_vector_type(4))) float floatx4;

union U16 { uint4 u; short8 s; };

__device__ __forceinline__ float hsig(float z) {
    return fminf(fmaxf(0.2f * z + 0.5f, 0.f), 1.f);
}

__device__ __forceinline__ float ftanh(float x) {
    float e = __expf(-2.f * fabsf(x));
    float t = (1.f - e) / (1.f + e);
    return copysignf(t, x);
}

__device__ __forceinline__ ushort f2bf(float f) {            // RNE fp32->bf16
    unsigned u = __float_as_uint(f);
    u = (u + 0x7fff + ((u >> 16) & 1)) >> 16;
    return (ushort)u;
}

// ---- prep: x fp32 -> bf16 (all T at once), layout [b,t,y,x,8] ----
__global__ __launch_bounds__(256) void conv_x_bf16(const float* __restrict__ x,
                                                   ushort* __restrict__ xbf, int n4) {
    int i = blockIdx.x * 256 + threadIdx.x;
    if (i >= n4) return;
    float4 v = ((const float4*)x)[i];
    ushort4 o;
    o.x = f2bf(v.x); o.y = f2bf(v.y); o.z = f2bf(v.z); o.w = f2bf(v.w);
    ((ushort4*)xbf)[i] = o;
}

// ---- prep: weights -> per-slice slab stream Bp[(slice*21+s)*256 + g*64 + lane] (16B units)
__global__ __launch_bounds__(256) void prep_w(const float* __restrict__ Wx,
                                              const float* __restrict__ Wh,
                                              ushort* __restrict__ Bp) {
    int idx = blockIdx.x * 256 + threadIdx.x;
    if (idx >= 4 * 21 * 256) return;                 // 21504
    int lane = idx & 63;
    int g = (idx >> 6) & 3;
    int rest = idx >> 8;                             // slice*21 + s
    int s = rest % 21, slice = rest / 21;
    int q = lane >> 4, col = lane & 15;
    int n = g * 64 + slice * 16 + col;
    ushort o[8];
    if (s < 18) {
        int tap = s >> 1;
        int cbase = (s & 1) * 32 + q * 8;
        #pragma unroll
        for (int j = 0; j < 8; ++j)
            o[j] = f2bf(Wh[((size_t)tap * FF + cbase + j) * G4 + n]);
    } else {
        int tap = (s - 18) * 4 + q;                  // packed x-taps; >8 -> zero pad
        #pragma unroll
        for (int j = 0; j < 8; ++j)
            o[j] = (tap < 9) ? f2bf(Wx[((size_t)tap * CINX + j) * G4 + n]) : (ushort)0;
    }
    U16 u;
    #pragma unroll
    for (int j = 0; j < 8; ++j) ((ushort*)&u)[j] = o[j];
    ((uint4*)Bp)[idx] = u.u;
}

// ---- main step kernel ----
__global__ __launch_bounds__(256, 4) void convlstm_mfma(
    const ushort* __restrict__ xbf, int t,
    const ushort* __restrict__ hS_in,     // [slice][pos][16] bf16
    ushort* __restrict__ hS_out,
    float* __restrict__ cS,               // [slice][pos][16] fp32
    const ushort* __restrict__ Bp,
    const float* __restrict__ bias,
    float* __restrict__ out, int last)
{
    __shared__ ushort hpatch[180 * HP];   // 18x10 halo, 64 h-ch (+8 pad)
    __shared__ ushort xpatch[180 * 8];    // 18x10 halo, 8 x-ch
    __shared__ ushort bslab[2][2048];     // double-buffered 4KB B slab

    const int tid = threadIdx.x;
    const int x0 = blockIdx.x * 8, y0 = blockIdx.y * 16;
    const int bb = blockIdx.z >> 2, slice = blockIdx.z & 3;

    // stage h halo patch from slice-major layout (8-ch granules)
    for (int e = tid; e < 1440; e += 256) {
        int part = e / 180, pp = e - part * 180;     // part = s8*2+half
        int py = pp / 10, px = pp - py * 10;
        int gy = y0 - 1 + py, gx = x0 - 1 + px;
        uint4 v = make_uint4(0, 0, 0, 0);
        if (gy >= 0 && gy < HTOT && gx >= 0 && gx < WTOT) {
            int s8 = part >> 1, half = part & 1;
            size_t gpos = ((size_t)bb * HTOT + gy) * WTOT + gx;
            v = *(const uint4*)(hS_in + ((size_t)s8 * NPOS + gpos) * 16 + half * 8);
        }
        *(uint4*)(hpatch + pp * HP + part * 8) = v;
    }
    if (tid < 180) {
        int py = tid / 10, px = tid - py * 10;
        int gy = y0 - 1 + py, gx = x0 - 1 + px;
        uint4 v = make_uint4(0, 0, 0, 0);
        if (gy >= 0 && gy < HTOT && gx >= 0 && gx < WTOT)
            v = *(const uint4*)(xbf + ((((size_t)bb * TT + t) * HTOT + gy) * WTOT + gx) * CINX);
        *(uint4*)(xpatch + tid * 8) = v;
    }

    const int w = tid >> 6, lane = tid & 63, q = lane >> 4, col = lane & 15;
    const uint4* Bp4 = (const uint4*)Bp;
    const int bslice = slice * 21;

    // preload slab 0
    uint4 vB = Bp4[(size_t)bslice * 256 + tid];
    ((uint4*)bslab[0])[tid] = vB;

    int pos0[2];
    #pragma unroll
    for (int mt = 0; mt < 2; ++mt)
        pos0[mt] = (w * 4 + mt * 2 + (col >> 3)) * 10 + (col & 7);

    floatx4 acc[2][4];
    #pragma unroll
    for (int g = 0; g < 4; ++g) {
        float bv = bias[g * 64 + slice * 16 + col];
        acc[0][g] = (floatx4){bv, bv, bv, bv};
        acc[1][g] = (floatx4){bv, bv, bv, bv};
    }

    __syncthreads();

    // ---- K-loop: 21 steps of K=32; B slab from LDS, next slab global->reg->LDS ----
    #pragma unroll
    for (int s = 0; s < 21; ++s) {
        if (s < 20) vB = Bp4[((size_t)bslice + s + 1) * 256 + tid];
        U16 b4[4], a4[2];
        #pragma unroll
        for (int g = 0; g < 4; ++g)
            b4[g].u = ((const uint4*)bslab[s & 1])[g * 64 + lane];
        if (s < 18) {
            int tap = s >> 1, kh = s & 1;
            int dy = tap / 3, dx = tap - 3 * dy;
            #pragma unroll
            for (int mt = 0; mt < 2; ++mt)
                a4[mt].u = *(const uint4*)(hpatch + (pos0[mt] + dy * 10 + dx) * HP + kh * 32 + q * 8);
        } else {
            int tap = (s - 18) * 4 + q; if (tap > 8) tap = 8;   // padded taps: B rows are 0
            int dy = tap / 3, dx = tap - 3 * dy;
            #pragma unroll
            for (int mt = 0; mt < 2; ++mt)
                a4[mt].u = *(const uint4*)(xpatch + (pos0[mt] + dy * 10 + dx) * 8);
        }
        #pragma unroll
        for (int mt = 0; mt < 2; ++mt)
            #pragma unroll
            for (int g = 0; g < 4; ++g)
                acc[mt][g] = __builtin_amdgcn_mfma_f32_16x16x32_bf16(a4[mt].s, b4[g].s, acc[mt][g], 0, 0, 0);
        if (s < 20) {
            ((uint4*)bslab[(s + 1) & 1])[tid] = vB;
            __syncthreads();
        }
    }

    // ---- epilogue: gates fused in-register; contiguous slice-major writes ----
    #pragma unroll
    for (int mt = 0; mt < 2; ++mt) {
        #pragma unroll
        for (int r = 0; r < 4; ++r) {
            int m = w * 32 + mt * 16 + q * 4 + r;     // 0..127
            int gy = y0 + (m >> 3), gx = x0 + (m & 7);
            size_t gpos = ((size_t)bb * HTOT + gy) * WTOT + gx;
            size_t idx = ((size_t)slice * NPOS + gpos) * 16 + col;
            float zi = acc[mt][0][r], zf = acc[mt][1][r];
            float zg = acc[mt][2][r], zo = acc[mt][3][r];
            float cn = hsig(zf) * cS[idx] + hsig(zi) * ftanh(zg);
            cS[idx] = cn;
            float hn = hsig(zo) * ftanh(cn);
            hS_out[idx] = f2bf(hn);
            if (last) out[gpos * 64 + slice * 16 + col] = hn;
        }
    }
}

extern "C" void kernel_launch(void* const* d_in, const int* in_sizes, int n_in,
                              void* d_out, int out_size, void* d_ws, size_t ws_size,
                              hipStream_t stream) {
    const float* x  = (const float*)d_in[0];
    const float* Wx = (const float*)d_in[1];
    const float* Wh = (const float*)d_in[2];
    const float* b  = (const float*)d_in[3];

    const size_t NX = (size_t)BB * TT * HTOT * WTOT * CINX;  // 9,437,184
    const size_t NH = (size_t)NPOS * FF;                     // 4,718,592

    char* ws = (char*)d_ws;
    ushort* xbf = (ushort*)ws;                  ws += NX * 2;            // 18.9 MB
    ushort* hS0 = (ushort*)ws;                  ws += NH * 2;            //  9.4 MB
    ushort* hS1 = (ushort*)ws;                  ws += NH * 2;            //  9.4 MB
    float*  cS  = (float*)ws;                   ws += NH * 4;            // 18.9 MB
    ushort* Bp  = (ushort*)ws;                                           // 336 KB

    hipMemsetAsync(hS0, 0, NH * 2, stream);
    hipMemsetAsync(cS,  0, NH * 4, stream);

    conv_x_bf16<<<(int)((NX / 4 + 255) / 256), 256, 0, stream>>>(x, xbf, (int)(NX / 4));
    prep_w<<<(4 * 21 * 256 + 255) / 256, 256, 0, stream>>>(Wx, Wh, Bp);

    dim3 grid(WTOT / 8, HTOT / 16, BB * 4);
    for (int t = 0; t < TT; ++t) {
        const ushort* hin = (t & 1) ? hS1 : hS0;
        ushort* hout      = (t & 1) ? hS0 : hS1;
        convlstm_mfma<<<grid, 256, 0, stream>>>(xbf, t, hin, hout, cS, Bp, b,
                                                (float*)d_out, t == TT - 1);
    }
}